// Round 12
// baseline (168.142 us; speedup 1.0000x reference)
//
#include <hip/hip_runtime.h>
#include <math.h>

// HoltWintersDecomposition: x (8192, 2048) f32, sequential per-row recurrence.
// r12 = r10 wave roles + ILP-2 producer + deferred-y:
//   - 256 blocks x 32 rows (one producer/consumer wave pair per CU).
//   - producer: lanes 0..15 each run TWO rows (L and L+16) interleaved. r11
//     showed the chain wave at ~34% issue occupancy (latency-bound); a second
//     independent chain per lane fills the bubbles (r4's lane-waste lesson
//     applies only to issue-bound waves).
//   - x staged by consumer into LDS; producer reads the whole tile upfront
//     (32 ds_read_b128, ~128 VGPR) -- one ~150cy lgkm wait per tile, hidden.
//   - deferred y: y_t = x_t * rl_t * rs_{t+1}; reuses next step's rcp(s_t+EPS)
//     and the xrl = x_t*rl_t product needed for s_t -> saves one rcp + one fma
//     per step. (l*s+EPS) vs (l+EPS)(s+EPS): rel diff <= EPS/s ~ 5% only where
//     s ~ 2e-7, abs error ~0.1 << 9.4e4 threshold. l/s arithmetic unchanged.
//   - consumer: x global->LDS prefetch (tile k+1) + transposed full-line
//     stores (tile k-1), as r10.
// Parallel-in-time (r6) is mathematically broken here (s ~ 20*EPS; EPS breaks
// the scale invariance) -- the serial chain stands.

constexpr int   T    = 2048;
constexpr int   B    = 8192;
constexpr int   RPB  = 32;        // rows per block
constexpr int   TT   = 64;        // steps per tile
constexpr int   NTI  = T / TT;    // 32 tiles
constexpr int   LSX  = 68;        // LDS stride words: 272B rows, 16B-aligned
constexpr float EPS  = 1e-8f;

// one recurrence step; optionally finalizes previous step's y into ys_
#define STEP1(lp_, sp_, xrl_, xt_, lv_, sv_, FIN_, ys_)                 \
  {                                                                     \
    const float rs_ = __builtin_amdgcn_rcpf(sp_ + EPS);                 \
    if (FIN_) { ys_ = xrl_ * rs_; }                                     \
    const float lt_ = __builtin_fmaf(oma, lp_, (alpha * xt_) * rs_);    \
    const float rl_ = __builtin_amdgcn_rcpf(lt_ + EPS);                 \
    xrl_ = xt_ * rl_;                                                   \
    const float st_ = __builtin_fmaf(gamma, xrl_, omg * sp_);           \
    lv_ = lt_; sv_ = st_;                                               \
    lp_ = lt_; sp_ = st_;                                               \
  }

__global__ __launch_bounds__(128, 1)
void hw_kernel(const float* __restrict__ x,
               const float* __restrict__ pla,
               const float* __restrict__ plg,
               float* __restrict__ out)
{
    __shared__ alignas(16) float XT[2][RPB][LSX];
    __shared__ alignas(16) float LT[2][RPB][LSX];
    __shared__ alignas(16) float ST[2][RPB][LSX];
    __shared__ alignas(16) float YT[2][RPB][LSX];

    const int tid  = threadIdx.x;
    const int wid  = tid >> 6;        // 0 = producer, 1 = consumer
    const int lane = tid & 63;
    const int row0 = blockIdx.x * RPB;

    const float alpha = 1.0f / (1.0f + expf(-pla[0]));
    const float gamma = 1.0f / (1.0f + expf(-plg[0]));
    const float oma = 1.0f - alpha, omg = 1.0f - gamma;

    float* __restrict__ lout = out;
    float* __restrict__ sout = out + (size_t)B * T;
    float* __restrict__ yout = out + (size_t)2 * B * T;

    const int cr = lane >> 4;          // 0..3
    const int cc = (lane & 15) << 2;   // 0,4,...,60

    auto load_x_tile = [&](int k) {
        const int bsel = k & 1;
        const int t1 = k * TT;
        #pragma unroll
        for (int it = 0; it < 8; ++it) {
            const int r = 4 * it + cr;
            const float4 v = *reinterpret_cast<const float4*>(
                &x[(size_t)(row0 + r) * T + t1 + cc]);
            *reinterpret_cast<float4*>(&XT[bsel][r][cc]) = v;
        }
    };

    auto store_tile = [&](int m, int itlo, int ithi) {
        const int bsel = m & 1;
        const int t0 = m * TT;
        for (int it = itlo; it < ithi; ++it) {
            const int r = 4 * it + cr;
            const size_t g = (size_t)(row0 + r) * T + t0 + cc;
            const float4 vl = *reinterpret_cast<const float4*>(&LT[bsel][r][cc]);
            const float4 vs = *reinterpret_cast<const float4*>(&ST[bsel][r][cc]);
            const float4 vy = *reinterpret_cast<const float4*>(&YT[bsel][r][cc]);
            *reinterpret_cast<float4*>(&lout[g]) = vl;
            *reinterpret_cast<float4*>(&sout[g]) = vs;
            *reinterpret_cast<float4*>(&yout[g]) = vy;
        }
    };

    if (wid == 0) {
        // ================= producer: 16 lanes x 2 rows =================
        const bool act = lane < 16;
        const int rA = lane & 15;        // row L
        const int rB = (lane & 15) + 16; // row L+16

        float lpA = 0.f, spA = 1.f, xrlA = 0.f;
        float lpB = 0.f, spB = 1.f, xrlB = 0.f;
        float4 yvA, yvB;

        auto run_tile = [&](int kk, bool firstTile) {
            const int bsel = kk & 1;
            float4 XA_[16], XB_[16];
            #pragma unroll
            for (int i = 0; i < 16; ++i)
                XA_[i] = *reinterpret_cast<const float4*>(&XT[bsel][rA][4 * i]);
            #pragma unroll
            for (int i = 0; i < 16; ++i)
                XB_[i] = *reinterpret_cast<const float4*>(&XT[bsel][rB][4 * i]);

            float4 lvA, svA, lvB, svB;
            #pragma unroll
            for (int g = 0; g < 16; ++g) {
                // ---- element 0
                if (g == 0 && firstTile) {
                    // t == 0: l0 = x0, s0 = 1; y0 finalized at step 1
                    const float x0A = XA_[0].x;
                    lpA = x0A; spA = 1.0f;
                    xrlA = x0A * __builtin_amdgcn_rcpf(x0A + EPS);
                    lvA.x = x0A; svA.x = 1.0f;
                    const float x0B = XB_[0].x;
                    lpB = x0B; spB = 1.0f;
                    xrlB = x0B * __builtin_amdgcn_rcpf(x0B + EPS);
                    lvB.x = x0B; svB.x = 1.0f;
                } else {
                    STEP1(lpA, spA, xrlA, XA_[g].x, lvA.x, svA.x, (g > 0), yvA.w)
                    STEP1(lpB, spB, xrlB, XB_[g].x, lvB.x, svB.x, (g > 0), yvB.w)
                }
                if (g > 0) {   // flush y group g-1 (slot3 just written)
                    *reinterpret_cast<float4*>(&YT[bsel][rA][4 * (g - 1)]) = yvA;
                    *reinterpret_cast<float4*>(&YT[bsel][rB][4 * (g - 1)]) = yvB;
                }
                // ---- elements 1..3
                STEP1(lpA, spA, xrlA, XA_[g].y, lvA.y, svA.y, true, yvA.x)
                STEP1(lpB, spB, xrlB, XB_[g].y, lvB.y, svB.y, true, yvB.x)
                STEP1(lpA, spA, xrlA, XA_[g].z, lvA.z, svA.z, true, yvA.y)
                STEP1(lpB, spB, xrlB, XB_[g].z, lvB.z, svB.z, true, yvB.y)
                STEP1(lpA, spA, xrlA, XA_[g].w, lvA.w, svA.w, true, yvA.z)
                STEP1(lpB, spB, xrlB, XB_[g].w, lvB.w, svB.w, true, yvB.z)
                // flush l/s group g
                *reinterpret_cast<float4*>(&LT[bsel][rA][4 * g]) = lvA;
                *reinterpret_cast<float4*>(&ST[bsel][rA][4 * g]) = svA;
                *reinterpret_cast<float4*>(&LT[bsel][rB][4 * g]) = lvB;
                *reinterpret_cast<float4*>(&ST[bsel][rB][4 * g]) = svB;
            }
            // tile epilogue: finalize y[63] with rs of the NEXT step (same value
            // the next tile's first STEP1 recomputes), flush y group 15
            yvA.w = xrlA * __builtin_amdgcn_rcpf(spA + EPS);
            yvB.w = xrlB * __builtin_amdgcn_rcpf(spB + EPS);
            *reinterpret_cast<float4*>(&YT[bsel][rA][60]) = yvA;
            *reinterpret_cast<float4*>(&YT[bsel][rB][60]) = yvB;
        };

        __syncthreads();                 // matches consumer's tile-0 load
        #pragma unroll 1
        for (int k = 0; k < NTI; ++k) {
            if (act) run_tile(k, k == 0);
            __syncthreads();
        }
    } else {
        // ================= consumer =================
        load_x_tile(0);
        __syncthreads();
        #pragma unroll 1
        for (int k = 0; k < NTI; ++k) {
            if (k + 1 < NTI) load_x_tile(k + 1);
            if (k > 0)       store_tile(k - 1, 0, 8);
            __syncthreads();
        }
    }

    // epilogue: tile 31 (buffer 1), both waves split the 8 store groups
    store_tile(NTI - 1, wid * 4, wid * 4 + 4);
}

extern "C" void kernel_launch(void* const* d_in, const int* in_sizes, int n_in,
                              void* d_out, int out_size, void* d_ws, size_t ws_size,
                              hipStream_t stream) {
    const float* x   = (const float*)d_in[0];
    const float* pla = (const float*)d_in[1];
    const float* plg = (const float*)d_in[2];
    float* out = (float*)d_out;

    dim3 grid(B / RPB);    // 256 blocks -> one producer/consumer pair per CU
    dim3 block(128);       // wave 0 = producer (16 lanes x 2 rows), wave 1 = consumer
    hw_kernel<<<grid, block, 0, stream>>>(x, pla, plg, out);
}

// Round 13
// 82.622 us; speedup vs baseline: 2.0351x; 2.0351x over previous
//
#include <hip/hip_runtime.h>
#include <math.h>

// HoltWintersDecomposition: x (8192, 2048) f32, sequential per-row recurrence.
// r13 = r11 structure + algebraically shortened dependent chain.
//   Chain per step reduced from add->rcp->mul->fma (x2) to rcp->fma (x2):
//    - fma regroup: lt = fma(axt, rs, cl), axt = alpha*xt (off-chain),
//      cl = fma(oma, lpe, EPS*alpha) (off-chain, computed during rcp latency).
//    - primed state lpe = l+EPS, spe = s+EPS: oma*lp + EPS = oma*lpe + EPS*alpha,
//      so the +EPS folds into the off-chain constant; rcp takes lpe/spe directly.
//   Outputs l = lpe-EPS, s = spe-EPS, y = x*rcp(fma(l,s,EPS)) are off-chain and
//   fill the rcp-latency bubbles. Exact-arithmetic-identical to the reference
//   recurrence (differences O(ulp), same class as v_rcp approx).
// Structure (r11, best at 87us): 256 blocks x 32 rows; producer wave = 32 lanes
// x 1 row, full-tile x register prefetch (1-tile distance covers barrier vmcnt
// drain); consumer wave = transposed full-line stores only; 1 barrier/tile.
// r12 lesson: never shrink active lanes (wave issue cost is per-wave, not
// per-lane); r9 lesson: producer global loads need >= 1-tile distance.
// Parallel-in-time (r6) is mathematically broken here (s ~ 20*EPS).

constexpr int   T    = 2048;
constexpr int   B    = 8192;
constexpr int   RPB  = 32;        // rows per block
constexpr int   TT   = 64;        // steps per tile
constexpr int   NTI  = T / TT;    // 32 tiles
constexpr int   LSX  = 68;        // LDS stride words: 272B rows, 16B-aligned
constexpr float EPS  = 1e-8f;

__global__ __launch_bounds__(128, 1)
void hw_kernel(const float* __restrict__ x,
               const float* __restrict__ pla,
               const float* __restrict__ plg,
               float* __restrict__ out)
{
    __shared__ alignas(16) float LT[2][RPB][LSX];
    __shared__ alignas(16) float ST[2][RPB][LSX];
    __shared__ alignas(16) float YT[2][RPB][LSX];

    const int tid  = threadIdx.x;
    const int wid  = tid >> 6;        // 0 = producer, 1 = consumer
    const int lane = tid & 63;
    const int row0 = blockIdx.x * RPB;

    const float alpha = 1.0f / (1.0f + expf(-pla[0]));
    const float gamma = 1.0f / (1.0f + expf(-plg[0]));
    const float oma = 1.0f - alpha, omg = 1.0f - gamma;
    const float EPSa = EPS * alpha;   // folds +EPS into the l fma constant
    const float EPSg = EPS * gamma;   // folds +EPS into the s fma constant

    float* __restrict__ lout = out;
    float* __restrict__ sout = out + (size_t)B * T;
    float* __restrict__ yout = out + (size_t)2 * B * T;

    // store-phase lane mapping (both waves use it in the epilogue)
    const int cr = lane >> 4;          // 0..3
    const int cc = (lane & 15) << 2;   // 0,4,...,60

    auto store_tile = [&](int m, int itlo, int ithi) {
        const int bsel = m & 1;
        const int t0 = m * TT;
        for (int it = itlo; it < ithi; ++it) {
            const int r = 4 * it + cr;
            const size_t g = (size_t)(row0 + r) * T + t0 + cc;
            const float4 vl = *reinterpret_cast<const float4*>(&LT[bsel][r][cc]);
            const float4 vs = *reinterpret_cast<const float4*>(&ST[bsel][r][cc]);
            const float4 vy = *reinterpret_cast<const float4*>(&YT[bsel][r][cc]);
            *reinterpret_cast<float4*>(&lout[g]) = vl;
            *reinterpret_cast<float4*>(&sout[g]) = vs;
            *reinterpret_cast<float4*>(&yout[g]) = vy;
        }
    };

    if (wid == 0) {
        // ================= producer =================
        const bool act = lane < RPB;
        const float* __restrict__ xrow = x + (size_t)(row0 + (act ? lane : 0)) * T;

        float lpe = 0.0f, spe = 1.0f;   // primed state: l+EPS, s+EPS
        float4 XA[16], XB[16];

        auto loadX = [&](float4* Xb, int k) {
            const float* p = xrow + k * TT;
            #pragma unroll
            for (int i = 0; i < 16; ++i)
                Xb[i] = *reinterpret_cast<const float4*>(p + 4 * i);
        };

        // chain: rcp -> fma -> rcp -> fma; everything else off-chain
        auto do_step = [&](float xt, float& lo, float& so, float& yo) {
            const float axt = alpha * xt;                         // off-chain
            const float gxt = gamma * xt;                         // off-chain
            const float cl  = __builtin_fmaf(oma, lpe, EPSa);     // off-chain
            const float rs  = __builtin_amdgcn_rcpf(spe);         // chain
            const float lte = __builtin_fmaf(axt, rs, cl);        // chain (= l_t+EPS)
            const float cs  = __builtin_fmaf(omg, spe, EPSg);     // off-chain
            const float rl  = __builtin_amdgcn_rcpf(lte);         // chain
            const float ste = __builtin_fmaf(gxt, rl, cs);        // chain (= s_t+EPS)
            const float lt  = lte - EPS;                          // off-chain
            const float st  = ste - EPS;                          // off-chain
            yo = xt * __builtin_amdgcn_rcpf(__builtin_fmaf(lt, st, EPS));
            lo = lt; so = st;
            lpe = lte; spe = ste;
        };

        auto compute_tile = [&](const float4* Xb, int k, bool first) {
            const int bsel = k & 1;
            #pragma unroll
            for (int g = 0; g < 16; ++g) {
                const float4 xv = Xb[g];
                float4 lv, sv, yv;
                if (first && g == 0) {
                    // t == 0: l0 = x0, s0 = 1, y0 = x0/(x0*1 + eps)
                    lv.x = xv.x; sv.x = 1.0f;
                    yv.x = xv.x * __builtin_amdgcn_rcpf(__builtin_fmaf(xv.x, 1.0f, EPS));
                    lpe = xv.x + EPS; spe = 1.0f + EPS;
                    do_step(xv.y, lv.y, sv.y, yv.y);
                    do_step(xv.z, lv.z, sv.z, yv.z);
                    do_step(xv.w, lv.w, sv.w, yv.w);
                } else {
                    do_step(xv.x, lv.x, sv.x, yv.x);
                    do_step(xv.y, lv.y, sv.y, yv.y);
                    do_step(xv.z, lv.z, sv.z, yv.z);
                    do_step(xv.w, lv.w, sv.w, yv.w);
                }
                *reinterpret_cast<float4*>(&LT[bsel][lane][4 * g]) = lv;
                *reinterpret_cast<float4*>(&ST[bsel][lane][4 * g]) = sv;
                *reinterpret_cast<float4*>(&YT[bsel][lane][4 * g]) = yv;
            }
        };

        if (act) { loadX(XA, 0); loadX(XB, 1); }
        if (act) compute_tile(XA, 0, true);     // one-time vmcnt wait on XA
        __syncthreads();

        #pragma unroll 1
        for (int k = 1; k < NTI - 1; k += 2) {
            if (act) { loadX(XA, k + 1); compute_tile(XB, k, false); }
            __syncthreads();
            if (act) { loadX(XB, k + 2); compute_tile(XA, k + 1, false); }
            __syncthreads();
        }
        if (act) compute_tile(XB, NTI - 1, false);
        __syncthreads();
    } else {
        // ================= consumer: stores only =================
        #pragma unroll 1
        for (int k = 0; k < NTI; ++k) {
            if (k > 0) store_tile(k - 1, 0, 8);
            __syncthreads();
        }
    }

    // epilogue: tile 31 (buffer 1), both waves split the 8 store groups
    store_tile(NTI - 1, wid * 4, wid * 4 + 4);
}

extern "C" void kernel_launch(void* const* d_in, const int* in_sizes, int n_in,
                              void* d_out, int out_size, void* d_ws, size_t ws_size,
                              hipStream_t stream) {
    const float* x   = (const float*)d_in[0];
    const float* pla = (const float*)d_in[1];
    const float* plg = (const float*)d_in[2];
    float* out = (float*)d_out;

    dim3 grid(B / RPB);    // 256 blocks -> one producer/consumer pair per CU
    dim3 block(128);       // wave 0 = producer (32 rows), wave 1 = consumer
    hw_kernel<<<grid, block, 0, stream>>>(x, pla, plg, out);
}